// Round 2
// baseline (107.150 us; speedup 1.0000x reference)
//
#include <hip/hip_runtime.h>
#include <stdint.h>

// DEQ: z_{t+1} = tanh(c + z_t @ B_w^T), c = x@A_w^T + A_b + B_b (fp32, computed once).
// ||B_w||_2 ~= 0.115 -> contraction; 5 Picard applications converge to ~6e-6 in y.
//
// Transposed MFMA 16x16x16_f16: z^T[s][b] = sum_k B_w[s][k] z^T[k][b].
//   Layout identity (r1): B-operand layout (k=quad*4+j, n=lane&15) == C/D layout
//   (row=quad*4+r, col=lane&15), so tanh(acc)+cvt_pkrtz IS the next B-fragment.
//   No cross-lane ops, no syncthreads in the loop.
//
// THIS ROUND: A-fragments (whole B_w, 128 regs) no longer held in registers.
//   Each MFMA reads its half4 A-fragment straight from LDS via ds_read_b64 with
//   a compile-time immediate offset (abase + mt*4352 + kt*32 bytes, max 30688
//   fits the 16-bit DS imm). Frees ~128 regs -> __launch_bounds__(256,4) ->
//   4 waves/SIMD instead of 2: latency hiding was the bottleneck (issue-bound
//   floor ~half of measured time). asm barrier on abase per application stops
//   LICM from re-hoisting the loads into registers (which would spill).

typedef _Float16 half4  __attribute__((ext_vector_type(4)));
typedef __fp16   fp16x2 __attribute__((ext_vector_type(2)));  // cvt_pkrtz native type
typedef float    f32x4  __attribute__((ext_vector_type(4)));

#define BW_STRIDE 136   // f16 elems per staged B_w row; bcol stride 272B -> 2-way bank alias (free)

union H2U { fp16x2 h; uint32_t u; };
union H4U { half4 h; uint32_t u[2]; };

__device__ __forceinline__ float tanh_fast(float v) {
    // tanh(v) = 1 - 2/(e^{2v}+1); v_exp_f32 + v_rcp_f32 (~1 ulp each)
    float e2 = __builtin_amdgcn_exp2f(v * 2.8853900817779268f); // 2*log2(e)
    return 1.0f - 2.0f * __builtin_amdgcn_rcpf(e2 + 1.0f);
}

__global__ __launch_bounds__(256, 4)
void deq_solve_kernel(const float* __restrict__ xin,
                      const float* __restrict__ A_w,
                      const float* __restrict__ A_b,
                      const float* __restrict__ B_w,
                      const float* __restrict__ B_b,
                      const float* __restrict__ h_w,
                      const float* __restrict__ h_b,
                      float* __restrict__ out)
{
    __shared__ __align__(16) _Float16 sb[128 * BW_STRIDE];

    const int tid  = threadIdx.x;
    const int lane = tid & 63;
    const int wv   = tid >> 6;
    const int quad = lane >> 4;
    const int bcol = lane & 15;

    // ---- one-time: stage B_w fp32 -> f16 LDS (coalesced float4) ----
    for (int i = tid; i < 4096; i += 256) {
        f32x4 v = ((const f32x4*)B_w)[i];
        int row = i >> 5, col = (i & 31) << 2;
        H2U h0, h1;
        h0.h = __builtin_amdgcn_cvt_pkrtz(v[0], v[1]);
        h1.h = __builtin_amdgcn_cvt_pkrtz(v[2], v[3]);
        *(uint32_t*)(sb + row * BW_STRIDE + col)     = h0.u;
        *(uint32_t*)(sb + row * BW_STRIDE + col + 2) = h1.u;
    }
    __syncthreads();

    // A-fragment base byte offset for this lane: A[m=bcol][k=quad*4+j]
    unsigned abase = (unsigned)((bcol * BW_STRIDE + quad * 4) * 2);

    // af(mt,kt) = B_w[mt*16 + bcol][kt*16 + quad*4 .. +3], read at the MFMA.
#define AFRAG(mt, kt) \
    (*(const half4*)((const char*)sb + abase + ((mt) * 16 * BW_STRIDE + (kt) * 16) * 2))

    // ---- c = x@A_w^T + A_b + B_b, fp32, in C-layout (computed once) ----
    const int gb = blockIdx.x * 64 + wv * 16 + bcol;
    const f32x4 xv = *(const f32x4*)(xin + 4 * gb);
    f32x4 cf[8];
    #pragma unroll
    for (int mt = 0; mt < 8; ++mt) {
        #pragma unroll
        for (int r = 0; r < 4; ++r) {
            int s = mt * 16 + quad * 4 + r;
            f32x4 aw = *(const f32x4*)(A_w + 4 * s);
            cf[mt][r] = A_b[s] + B_b[s] + aw[0]*xv[0] + aw[1]*xv[1] + aw[2]*xv[2] + aw[3]*xv[3];
        }
    }

    half4 bf[8];   // B-fragments == tanh(acc) packed; bf[kt] comes from acc[mt=kt]

#define EPILOGUE(ACC)                                                      \
    _Pragma("unroll")                                                      \
    for (int mt = 0; mt < 8; ++mt) {                                       \
        H2U pa, pb;                                                        \
        pa.h = __builtin_amdgcn_cvt_pkrtz(tanh_fast((ACC)[mt][0]),         \
                                          tanh_fast((ACC)[mt][1]));        \
        pb.h = __builtin_amdgcn_cvt_pkrtz(tanh_fast((ACC)[mt][2]),         \
                                          tanh_fast((ACC)[mt][3]));        \
        H4U w; w.u[0] = pa.u; w.u[1] = pb.u;                               \
        bf[mt] = w.h;                                                      \
    }

#define MFMA_CHAIN(ACC)                                                    \
    _Pragma("unroll")                                                      \
    for (int mt = 0; mt < 8; ++mt)                                         \
        (ACC)[mt] = __builtin_amdgcn_mfma_f32_16x16x16f16(AFRAG(mt, 0), bf[0], cf[mt], 0, 0, 0); \
    _Pragma("unroll")                                                      \
    for (int kt = 1; kt < 8; ++kt)                                         \
        _Pragma("unroll")                                                  \
        for (int mt = 0; mt < 8; ++mt)                                     \
            (ACC)[mt] = __builtin_amdgcn_mfma_f32_16x16x16f16(AFRAG(mt, kt), bf[kt], (ACC)[mt], 0, 0, 0);

    // ---- application 1: z1 = tanh(c) ----
    EPILOGUE(cf)

    // ---- applications 2..4 ----
    #pragma unroll 1
    for (int it = 0; it < 3; ++it) {
        asm volatile("" : "+v"(abase));   // block LICM/CSE of AFRAG loads across apps
        f32x4 acc[8];
        MFMA_CHAIN(acc)
        EPILOGUE(acc)
    }

    // ---- application 5 fused with output: y = h_w . tanh(acc) + h_b ----
    float partial = 0.f;
    {
        asm volatile("" : "+v"(abase));
        f32x4 acc[8];
        MFMA_CHAIN(acc)
        #pragma unroll
        for (int mt = 0; mt < 8; ++mt) {
            f32x4 hw = *(const f32x4*)(h_w + mt * 16 + quad * 4);
            #pragma unroll
            for (int r = 0; r < 4; ++r)
                partial += tanh_fast(acc[mt][r]) * hw[r];
        }
    }
    partial += __shfl_xor(partial, 16);
    partial += __shfl_xor(partial, 32);
    if (quad == 0)
        out[gb] = partial + h_b[0];
}

extern "C" void kernel_launch(void* const* d_in, const int* in_sizes, int n_in,
                              void* d_out, int out_size, void* d_ws, size_t ws_size,
                              hipStream_t stream) {
    const float* x   = (const float*)d_in[0];
    const float* A_w = (const float*)d_in[1];
    const float* A_b = (const float*)d_in[2];
    const float* B_w = (const float*)d_in[3];
    const float* B_b = (const float*)d_in[4];
    const float* h_w = (const float*)d_in[5];
    const float* h_b = (const float*)d_in[6];
    float* outp = (float*)d_out;

    int batch = in_sizes[0] / 4;   // 131072
    int grid  = batch / 64;        // 64 batch rows per block (4 waves x 16)
    deq_solve_kernel<<<grid, 256, 0, stream>>>(x, A_w, A_b, B_w, B_b, h_w, h_b, outp);
}

// Round 3
// 105.185 us; speedup vs baseline: 1.0187x; 1.0187x over previous
//
#include <hip/hip_runtime.h>
#include <stdint.h>

// DEQ: z_{t+1} = tanh(c + z_t @ B_w^T), c = x@A_w^T + A_b + B_b (fp32, computed once).
// ||B_w||_2 ~= 0.115 -> contraction; 5 Picard applications converge to ~6e-6 in y.
//
// Transposed MFMA 16x16x16_f16: z^T[s][b] = sum_k B_w[s][k] z^T[k][b].
//   Layout identity (r1, verified): B-operand layout (k=quad*4+j, n=lane&15) ==
//   C/D layout (row=quad*4+r, col=lane&15), so tanh(acc)+cvt_pkrtz written
//   state-contiguous IS the next B-fragment (b64 read).
//
// THIS ROUND: state-split across waves. r1 (B_w in 128 regs) was stuck at
//   2 waves/SIMD; r2 (B_w fragments from LDS) saturated the per-CU LDS pipe
//   (1024 ds_read_b64/wave, conflicts 8.4M). Now wave w owns states
//   [32w,32w+32) x 32 batch: af = 32 regs only (direct global load, B_w is
//   L2-resident), and waves exchange z via a tiny ping-pong LDS buffer
//   (4 b64 writes + 16 b64 reads per wave per app, 1 barrier per app).
//   ~30x less LDS traffic than r2 AND 4 waves/SIMD. Work is conserved.

typedef _Float16 half4  __attribute__((ext_vector_type(4)));
typedef __fp16   fp16x2 __attribute__((ext_vector_type(2)));  // cvt_pkrtz native type
typedef float    f32x4  __attribute__((ext_vector_type(4)));

#define ZS 132   // f16 per z-exchange row: [batch 32][state 128 + 4 pad] (264B rows, 8B aligned)

union H2U { fp16x2 h; uint32_t u; };
union H4U { half4 h; uint32_t u[2]; };

__device__ __forceinline__ float tanh_fast(float v) {
    // tanh(v) = 1 - 2/(e^{2v}+1); v_exp_f32 + v_rcp_f32 (~1 ulp each)
    float e2 = __builtin_amdgcn_exp2f(v * 2.8853900817779268f); // 2*log2(e)
    return 1.0f - 2.0f * __builtin_amdgcn_rcpf(e2 + 1.0f);
}

__global__ __launch_bounds__(256, 4)
void deq_solve_kernel(const float* __restrict__ xin,
                      const float* __restrict__ A_w,
                      const float* __restrict__ A_b,
                      const float* __restrict__ B_w,
                      const float* __restrict__ B_b,
                      const float* __restrict__ h_w,
                      const float* __restrict__ h_b,
                      float* __restrict__ out)
{
    __shared__ __align__(16) _Float16 zex[2][32 * ZS];  // ping-pong z, [batch][state]
    __shared__ float red[4][32];                        // cross-wave output reduction

    const int tid  = threadIdx.x;
    const int lane = tid & 63;
    const int wv   = tid >> 6;       // wave owns states [32*wv, 32*wv+32)
    const int quad = lane >> 4;
    const int bcol = lane & 15;

    // ---- af(mt,kt): B_w[32wv+16mt+bcol][16kt+4quad+j], f32->f16 direct from
    //      global (64KB total, L2/L3-resident; no LDS staging). 32 VGPRs.
    half4 af[2][8];
    #pragma unroll
    for (int mt = 0; mt < 2; ++mt) {
        const f32x4* rowp = (const f32x4*)(B_w + (wv * 32 + mt * 16 + bcol) * 128 + quad * 4);
        #pragma unroll
        for (int kt = 0; kt < 8; ++kt) {
            f32x4 v = rowp[kt * 4];
            H2U a, b; H4U w;
            a.h = __builtin_amdgcn_cvt_pkrtz(v[0], v[1]);
            b.h = __builtin_amdgcn_cvt_pkrtz(v[2], v[3]);
            w.u[0] = a.u; w.u[1] = b.u;
            af[mt][kt] = w.h;
        }
    }

    // ---- cf(mt,nt): c for state s = 32wv+16mt+4quad+r, batch b0+16nt+bcol ----
    const int b0 = blockIdx.x * 32;
    f32x4 xv[2];
    #pragma unroll
    for (int nt = 0; nt < 2; ++nt)
        xv[nt] = *(const f32x4*)(xin + 4 * (b0 + nt * 16 + bcol));
    f32x4 cf[2][2];
    #pragma unroll
    for (int mt = 0; mt < 2; ++mt) {
        #pragma unroll
        for (int r = 0; r < 4; ++r) {
            int s = wv * 32 + mt * 16 + quad * 4 + r;
            f32x4 aw = *(const f32x4*)(A_w + 4 * s);
            float bias = A_b[s] + B_b[s];
            #pragma unroll
            for (int nt = 0; nt < 2; ++nt)
                cf[mt][nt][r] = bias + aw[0]*xv[nt][0] + aw[1]*xv[nt][1]
                                     + aw[2]*xv[nt][2] + aw[3]*xv[nt][3];
        }
    }

    half4 bf[8][2];   // B-fragments: full 128 states x 2 batch tiles

    // tanh + pack + write own state-slice to zex[BUF] (state-contiguous b64)
#define EPILOGUE(ACC, BUF)                                                     \
    _Pragma("unroll")                                                          \
    for (int mt = 0; mt < 2; ++mt)                                             \
        _Pragma("unroll")                                                      \
        for (int nt = 0; nt < 2; ++nt) {                                       \
            H2U pa, pb; H4U w;                                                 \
            pa.h = __builtin_amdgcn_cvt_pkrtz(tanh_fast((ACC)[mt][nt][0]),     \
                                              tanh_fast((ACC)[mt][nt][1]));    \
            pb.h = __builtin_amdgcn_cvt_pkrtz(tanh_fast((ACC)[mt][nt][2]),     \
                                              tanh_fast((ACC)[mt][nt][3]));    \
            w.u[0] = pa.u; w.u[1] = pb.u;                                      \
            *(half4*)(&zex[BUF][(nt * 16 + bcol) * ZS + wv * 32 + mt * 16 + quad * 4]) = w.h; \
        }

#define LOADBF(BUF)                                                            \
    _Pragma("unroll")                                                          \
    for (int kt = 0; kt < 8; ++kt)                                             \
        _Pragma("unroll")                                                      \
        for (int nt = 0; nt < 2; ++nt)                                         \
            bf[kt][nt] = *(const half4*)(&zex[BUF][(nt * 16 + bcol) * ZS + kt * 16 + quad * 4]);

#define MFMA_CHAIN(ACC)                                                        \
    _Pragma("unroll")                                                          \
    for (int mt = 0; mt < 2; ++mt)                                             \
        _Pragma("unroll")                                                      \
        for (int nt = 0; nt < 2; ++nt)                                         \
            (ACC)[mt][nt] = __builtin_amdgcn_mfma_f32_16x16x16f16(af[mt][0], bf[0][nt], cf[mt][nt], 0, 0, 0); \
    _Pragma("unroll")                                                          \
    for (int kt = 1; kt < 8; ++kt)                                             \
        _Pragma("unroll")                                                      \
        for (int mt = 0; mt < 2; ++mt)                                         \
            _Pragma("unroll")                                                  \
            for (int nt = 0; nt < 2; ++nt)                                     \
                (ACC)[mt][nt] = __builtin_amdgcn_mfma_f32_16x16x16f16(af[mt][kt], bf[kt][nt], (ACC)[mt][nt], 0, 0, 0);

    // ---- application 1: z1 = tanh(c) ----
    EPILOGUE(cf, 0)
    __syncthreads();

    // ---- applications 2..4 (ping-pong; one barrier per app) ----
    {
        f32x4 acc[2][2];
        LOADBF(0) MFMA_CHAIN(acc) EPILOGUE(acc, 1) __syncthreads();
        LOADBF(1) MFMA_CHAIN(acc) EPILOGUE(acc, 0) __syncthreads();
        LOADBF(0) MFMA_CHAIN(acc) EPILOGUE(acc, 1) __syncthreads();
    }

    // ---- application 5 fused with output: y = h_w . tanh(acc) + h_b ----
    float part0 = 0.f, part1 = 0.f;
    {
        f32x4 acc[2][2];
        LOADBF(1)
        MFMA_CHAIN(acc)
        #pragma unroll
        for (int mt = 0; mt < 2; ++mt) {
            f32x4 hw = *(const f32x4*)(h_w + wv * 32 + mt * 16 + quad * 4);
            #pragma unroll
            for (int r = 0; r < 4; ++r) {
                part0 += tanh_fast(acc[mt][0][r]) * hw[r];
                part1 += tanh_fast(acc[mt][1][r]) * hw[r];
            }
        }
    }
    // reduce over the 4 quads (butterfly) -> every lane holds full wave-partials
    part0 += __shfl_xor(part0, 16); part0 += __shfl_xor(part0, 32);
    part1 += __shfl_xor(part1, 16); part1 += __shfl_xor(part1, 32);
    if (lane < 32)
        red[wv][lane] = (lane < 16) ? part0 : part1;
    __syncthreads();
    if (tid < 32)
        out[b0 + tid] = red[0][tid] + red[1][tid] + red[2][tid] + red[3][tid] + h_b[0];
}

extern "C" void kernel_launch(void* const* d_in, const int* in_sizes, int n_in,
                              void* d_out, int out_size, void* d_ws, size_t ws_size,
                              hipStream_t stream) {
    const float* x   = (const float*)d_in[0];
    const float* A_w = (const float*)d_in[1];
    const float* A_b = (const float*)d_in[2];
    const float* B_w = (const float*)d_in[3];
    const float* B_b = (const float*)d_in[4];
    const float* h_w = (const float*)d_in[5];
    const float* h_b = (const float*)d_in[6];
    float* outp = (float*)d_out;

    int batch = in_sizes[0] / 4;   // 131072
    int grid  = batch / 32;        // 32 batch per block (4 waves, state-split)
    deq_solve_kernel<<<grid, 256, 0, stream>>>(x, A_w, A_b, B_w, B_b, h_w, h_b, outp);
}